// Round 4
// baseline (800.468 us; speedup 1.0000x reference)
//
#include <hip/hip_runtime.h>
#include <hip/hip_bf16.h>

using bf16 = __hip_bfloat16;
using bf16x8 = __attribute__((ext_vector_type(8))) __bf16;
using f32x4  = __attribute__((ext_vector_type(4))) float;
typedef unsigned short ushort_t;

#define BM 128
#define BN 128
#define BK 32

// B=4, L=512, D=768, W=12, K_spans=6144, rows_out = B*K = 24576

__device__ __forceinline__ void gl_lds16(const void* g, void* l) {
  __builtin_amdgcn_global_load_lds(
      (const __attribute__((address_space(1))) void*)g,
      (__attribute__((address_space(3))) void*)l, 16, 0, 0);
}

__device__ __forceinline__ ushort_t f2bf(float f) {  // RNE fp32->bf16
  unsigned u = __float_as_uint(f);
  u += 0x7FFF + ((u >> 16) & 1);
  return (ushort_t)(u >> 16);
}

// flags[0]=1 if float inputs are stored as bf16 (else fp32)
// flags[1]=1 if span_idx is int64 (else int32)
__global__ void sniff(const unsigned* __restrict__ w1,
                      const unsigned* __restrict__ idx, int* flags) {
  __shared__ int cnt[2];
  if (threadIdx.x == 0) { cnt[0] = 0; cnt[1] = 0; }
  __syncthreads();
  int t = threadIdx.x;  // 256 threads
  int c0 = 0;
  for (int k = 0; k < 4; ++k) {
    unsigned lo = w1[t * 4 + k] & 0xFFFFu;      // low 16 bits of word
    unsigned e = (lo >> 7) & 0xFF;              // bf16 exponent field
    if (e <= 122) c0++;                         // |x| < 0.0625 => plausible weight
  }
  int c1 = (idx[2 * t + 1] != 0) ? 1 : 0;       // odd words: 0 for int64 hi-words
  atomicAdd(&cnt[0], c0);
  atomicAdd(&cnt[1], c1);
  __syncthreads();
  if (threadIdx.x == 0) {
    flags[0] = (cnt[0] >= 900) ? 1 : 0;  // bf16 storage: all 1024 pass; fp32: ~490
    flags[1] = (cnt[1] == 0) ? 1 : 0;
  }
}

__global__ void norm_idx(const int* __restrict__ flags, const void* __restrict__ src,
                         int* __restrict__ dst) {
  int i = blockIdx.x * 256 + threadIdx.x;  // grid covers exactly 49152
  int v = flags[1] ? (int)((const long long*)src)[i] : ((const int*)src)[i];
  dst[i] = v;
}

// n must be a multiple of 1024; grid = n/1024, block = 256, 4 elems/thread
__global__ void cvt_bf16(const int* __restrict__ flags, const void* __restrict__ src,
                         ushort_t* __restrict__ dst) {
  long i = (long)(blockIdx.x * 256 + threadIdx.x) * 4;
  if (flags[0]) {  // already bf16: raw copy
    *(ushort4*)(dst + i) = *((const ushort4*)((const ushort_t*)src + i));
  } else {         // fp32 -> bf16
    float4 f = ((const float4*)src)[i >> 2];
    ushort4 o;
    o.x = f2bf(f.x); o.y = f2bf(f.y); o.z = f2bf(f.z); o.w = f2bf(f.w);
    *(ushort4*)(dst + i) = o;
  }
}

// biases -> fp32, concatenated [bs1|bs2|be1|be2|bo1|bo2] = 11520 floats
__global__ void cvt_bias(const int* __restrict__ flags,
                         const void* b0, const void* b1, const void* b2,
                         const void* b3, const void* b4, const void* b5,
                         float* __restrict__ dst) {
  int i = blockIdx.x * 256 + threadIdx.x;
  if (i >= 11520) return;
  const void* src; int off;
  if (i < 3072)       { src = b0; off = i; }
  else if (i < 3840)  { src = b1; off = i - 3072; }
  else if (i < 6912)  { src = b2; off = i - 3840; }
  else if (i < 7680)  { src = b3; off = i - 6912; }
  else if (i < 10752) { src = b4; off = i - 7680; }
  else                { src = b5; off = i - 10752; }
  dst[i] = flags[0] ? __bfloat162float(((const bf16*)src)[off])
                    : ((const float*)src)[off];
}

// C[M,N] = act(A[M,K] @ Bw[N,K]^T + bias), A optionally gathered from repS/repE
// OUTF32: C is float* (reference output dtype), else bf16*
template <bool GATHER, bool RELU, bool OUTF32>
__global__ __launch_bounds__(256) void gemm_bt(
    const bf16* __restrict__ A,
    const bf16* __restrict__ repS, const bf16* __restrict__ repE,
    const int* __restrict__ sidx, int row_base,
    const bf16* __restrict__ Bw, const float* __restrict__ bias,
    void* __restrict__ C, int N, int Kdim) {
  __shared__ bf16 lA[BM * BK];  // 8 KB, row-major [row][k], no pad (global_load_lds)
  __shared__ bf16 lB[BN * BK];  // 8 KB

  const int tid  = threadIdx.x;
  const int lane = tid & 63;
  const int wave = tid >> 6;
  const int wm = wave >> 1, wn = wave & 1;  // 2x2 waves, each 64x64
  const int m0 = blockIdx.y * BM;
  const int n0 = blockIdx.x * BN;

  // staging: thread covers rows (tid>>2) and (tid>>2)+64, 8 elements at (tid&3)*8
  const int srow = tid >> 2;
  const int scol = (tid & 3) * 8;

  const bf16 *a0 = nullptr, *a1 = nullptr;
  const bf16 *pS0 = nullptr, *pE0 = nullptr, *pS1 = nullptr, *pE1 = nullptr;
  if (GATHER) {
    int r0 = row_base + m0 + srow;
    int r1 = r0 + 64;
    int b0 = r0 / 6144, b1 = r1 / 6144;
    int s0 = min(max(sidx[2 * r0], 0), 511);
    int e0 = min(max(sidx[2 * r0 + 1], 0), 511);
    int s1 = min(max(sidx[2 * r1], 0), 511);
    int e1 = min(max(sidx[2 * r1 + 1], 0), 511);
    pS0 = repS + ((size_t)b0 * 512 + s0) * 768 + scol;
    pE0 = repE + ((size_t)b0 * 512 + e0) * 768 + scol;
    pS1 = repS + ((size_t)b1 * 512 + s1) * 768 + scol;
    pE1 = repE + ((size_t)b1 * 512 + e1) * 768 + scol;
  } else {
    a0 = A + (size_t)(m0 + srow) * Kdim + scol;
    a1 = a0 + (size_t)64 * Kdim;
  }
  const bf16* b0p = Bw + (size_t)(n0 + srow) * Kdim + scol;
  const bf16* b1p = b0p + (size_t)64 * Kdim;

  f32x4 acc[4][4];
  const f32x4 z = {0.f, 0.f, 0.f, 0.f};
#pragma unroll
  for (int i = 0; i < 4; ++i)
#pragma unroll
    for (int j = 0; j < 4; ++j) acc[i][j] = z;

  const int fr = lane & 15;        // m (A) / n (B) within 16-tile
  const int fk = (lane >> 4) * 8;  // k offset

  for (int k0 = 0; k0 < Kdim; k0 += BK) {
    const bf16 *sa0, *sa1;
    if (GATHER) {
      if (k0 < 768) { sa0 = pS0 + k0; sa1 = pS1 + k0; }
      else          { sa0 = pE0 + (k0 - 768); sa1 = pE1 + (k0 - 768); }
    } else {
      sa0 = a0 + k0; sa1 = a1 + k0;
    }
    gl_lds16(sa0, lA + tid * 8);
    gl_lds16(sa1, lA + 2048 + tid * 8);
    gl_lds16(b0p + k0, lB + tid * 8);
    gl_lds16(b1p + k0, lB + 2048 + tid * 8);
    __syncthreads();  // drains vmcnt -> LDS writes visible

    bf16x8 af[4], bv[4];
#pragma unroll
    for (int i = 0; i < 4; ++i)
      af[i] = *(const bf16x8*)(const void*)(lA + (wm * 64 + i * 16 + fr) * BK + fk);
#pragma unroll
    for (int j = 0; j < 4; ++j)
      bv[j] = *(const bf16x8*)(const void*)(lB + (wn * 64 + j * 16 + fr) * BK + fk);
#pragma unroll
    for (int i = 0; i < 4; ++i)
#pragma unroll
      for (int j = 0; j < 4; ++j)
        acc[i][j] = __builtin_amdgcn_mfma_f32_16x16x32_bf16(af[i], bv[j], acc[i][j], 0, 0, 0);
    __syncthreads();  // protect LDS before next stage
  }

  // epilogue: C/D layout col=lane&15 (n), row=(lane>>4)*4+reg (m)
  float* Cf = (float*)C;
  bf16*  Cb = (bf16*)C;
#pragma unroll
  for (int j = 0; j < 4; ++j) {
    int n = n0 + wn * 64 + j * 16 + fr;
    float bj = bias[n];
#pragma unroll
    for (int i = 0; i < 4; ++i) {
      int mb = m0 + wm * 64 + i * 16 + (lane >> 4) * 4;
#pragma unroll
      for (int r = 0; r < 4; ++r) {
        float v = acc[i][j][r] + bj;
        if (RELU) v = fmaxf(v, 0.f);
        if (OUTF32) Cf[(size_t)(mb + r) * N + n] = v;
        else        Cb[(size_t)(mb + r) * N + n] = __float2bfloat16(v);
      }
    }
  }
}

extern "C" void kernel_launch(void* const* d_in, const int* in_sizes, int n_in,
                              void* d_out, int out_size, void* d_ws, size_t ws_size,
                              hipStream_t stream) {
  const void* h    = d_in[0];
  const void* sidx = d_in[1];
  const void *ws1 = d_in[2],  *bs1 = d_in[3];
  const void *ws2 = d_in[4],  *bs2 = d_in[5];
  const void *we1 = d_in[6],  *be1 = d_in[7];
  const void *we2 = d_in[8],  *be2 = d_in[9];
  const void *wo1 = d_in[10], *bo1 = d_in[11];
  const void *wo2 = d_in[12], *bo2 = d_in[13];

  // ---- workspace layout (bytes) ----
  char* p = (char*)d_ws;
  int*      flags = (int*)p;                 // 2 ints (+pad)
  int*      idx32 = (int*)(p + 256);         // 49152 ints = 196608 B
  float*    biasf = (float*)(p + 256 + 196608);            // 11520 f32 (pad to 49152)
  ushort_t* hb    = (ushort_t*)(p + 256 + 196608 + 49152); // 1572864 bf16
  ushort_t* w1sb  = hb   + (size_t)1572864;
  ushort_t* w2sb  = w1sb + (size_t)2359296;
  ushort_t* w1eb  = w2sb + (size_t)2359296;
  ushort_t* w2eb  = w1eb + (size_t)2359296;
  ushort_t* wo1b  = w2eb + (size_t)2359296;
  ushort_t* wo2b  = wo1b + (size_t)4718592;
  ushort_t* repS  = wo2b + (size_t)2359296;
  ushort_t* repE  = repS + (size_t)1572864;
  ushort_t* scr   = repE + (size_t)1572864;
  size_t fixed = (size_t)((char*)scr - (char*)d_ws);
  if (ws_size < fixed + (size_t)128 * 3072 * 2) return;  // clean failure
  long long c = (long long)((ws_size - fixed) / ((size_t)3072 * 2));
  c = (c / 128) * 128;
  long long cT = c < 2048 ? c : 2048;
  long long cO = c < 24576 ? c : 24576;

  dim3 blk(256);
  // ---- dtype sniff + normalization ----
  sniff<<<1, blk, 0, stream>>>((const unsigned*)ws1, (const unsigned*)sidx, flags);
  norm_idx<<<192, blk, 0, stream>>>(flags, sidx, idx32);
  cvt_bf16<<<1536, blk, 0, stream>>>(flags, h,   hb);
  cvt_bf16<<<2304, blk, 0, stream>>>(flags, ws1, w1sb);
  cvt_bf16<<<2304, blk, 0, stream>>>(flags, ws2, w2sb);
  cvt_bf16<<<2304, blk, 0, stream>>>(flags, we1, w1eb);
  cvt_bf16<<<2304, blk, 0, stream>>>(flags, we2, w2eb);
  cvt_bf16<<<4608, blk, 0, stream>>>(flags, wo1, wo1b);
  cvt_bf16<<<2304, blk, 0, stream>>>(flags, wo2, wo2b);
  cvt_bias<<<45, blk, 0, stream>>>(flags, bs1, bs2, be1, be2, bo1, bo2, biasf);
  const float *bs1f = biasf, *bs2f = biasf + 3072, *be1f = biasf + 3840,
              *be2f = biasf + 6912, *bo1f = biasf + 7680, *bo2f = biasf + 10752;

  // ---- Phase A: token MLPs -> repS, repE (chunked over 2048 token rows) ----
  for (long long r = 0; r < 2048; r += cT) {
    long long mc = 2048 - r < cT ? 2048 - r : cT;
    dim3 g1(24, mc / 128), g2(6, mc / 128);
    gemm_bt<false, true, false><<<g1, blk, 0, stream>>>(
        (const bf16*)hb + r * 768, nullptr, nullptr, nullptr, 0,
        (const bf16*)w1sb, bs1f, scr, 3072, 768);
    gemm_bt<false, true, false><<<g2, blk, 0, stream>>>(
        (const bf16*)scr, nullptr, nullptr, nullptr, 0,
        (const bf16*)w2sb, bs2f, (bf16*)repS + r * 768, 768, 3072);
    gemm_bt<false, true, false><<<g1, blk, 0, stream>>>(
        (const bf16*)hb + r * 768, nullptr, nullptr, nullptr, 0,
        (const bf16*)w1eb, be1f, scr, 3072, 768);
    gemm_bt<false, true, false><<<g2, blk, 0, stream>>>(
        (const bf16*)scr, nullptr, nullptr, nullptr, 0,
        (const bf16*)w2eb, be2f, (bf16*)repE + r * 768, 768, 3072);
  }
  // ---- Phase B: output MLP over 24576 span rows; final GEMM writes fp32 ----
  float* outf = (float*)d_out;
  for (long long r = 0; r < 24576; r += cO) {
    long long mc = 24576 - r < cO ? 24576 - r : cO;
    gemm_bt<true, true, false><<<dim3(24, mc / 128), blk, 0, stream>>>(
        nullptr, (const bf16*)repS, (const bf16*)repE, idx32, (int)r,
        (const bf16*)wo1b, bo1f, scr, 3072, 1536);
    gemm_bt<false, false, true><<<dim3(6, mc / 128), blk, 0, stream>>>(
        (const bf16*)scr, nullptr, nullptr, nullptr, 0,
        (const bf16*)wo2b, bo2f, outf + (size_t)r * 768, 768, 3072);
  }
}

// Round 5
// 700.571 us; speedup vs baseline: 1.1426x; 1.1426x over previous
//
#include <hip/hip_runtime.h>
#include <hip/hip_bf16.h>

using bf16 = __hip_bfloat16;
using bf16x8 = __attribute__((ext_vector_type(8))) __bf16;
using f32x4  = __attribute__((ext_vector_type(4))) float;
typedef unsigned short ushort_t;

#define BM 128
#define BN 128
#define BK 32

// B=4, L=512, D=768, W=12, K_spans=6144, rows_out = B*K = 24576

__device__ __forceinline__ void gl_lds16(const void* g, void* l) {
  __builtin_amdgcn_global_load_lds(
      (const __attribute__((address_space(1))) void*)g,
      (__attribute__((address_space(3))) void*)l, 16, 0, 0);
}

__device__ __forceinline__ ushort_t f2bf(float f) {  // RNE fp32->bf16
  unsigned u = __float_as_uint(f);
  u += 0x7FFF + ((u >> 16) & 1);
  return (ushort_t)(u >> 16);
}

// flags[0]=1 if float inputs are stored as bf16 (else fp32)
// flags[1]=1 if span_idx is int64 (else int32)
__global__ void sniff(const unsigned* __restrict__ w1,
                      const unsigned* __restrict__ idx, int* flags) {
  __shared__ int cnt[2];
  if (threadIdx.x == 0) { cnt[0] = 0; cnt[1] = 0; }
  __syncthreads();
  int t = threadIdx.x;  // 256 threads
  int c0 = 0;
  for (int k = 0; k < 4; ++k) {
    unsigned lo = w1[t * 4 + k] & 0xFFFFu;      // low 16 bits of word
    unsigned e = (lo >> 7) & 0xFF;              // bf16 exponent field
    if (e <= 122) c0++;                         // |x| < 0.0625 => plausible weight
  }
  int c1 = (idx[2 * t + 1] != 0) ? 1 : 0;       // odd words: 0 for int64 hi-words
  atomicAdd(&cnt[0], c0);
  atomicAdd(&cnt[1], c1);
  __syncthreads();
  if (threadIdx.x == 0) {
    flags[0] = (cnt[0] >= 900) ? 1 : 0;  // bf16 storage: all 1024 pass; fp32: ~490
    flags[1] = (cnt[1] == 0) ? 1 : 0;
  }
}

__global__ void norm_idx(const int* __restrict__ flags, const void* __restrict__ src,
                         int* __restrict__ dst) {
  int i = blockIdx.x * 256 + threadIdx.x;  // grid covers exactly 49152
  int v = flags[1] ? (int)((const long long*)src)[i] : ((const int*)src)[i];
  dst[i] = v;
}

// One kernel converts h + all 6 weights into the contiguous bf16 region at dst.
// Region boundaries are all multiples of 1024 elements -> block-uniform source.
__global__ void cvt_all(const int* __restrict__ flags,
                        const void* s0, const void* s1, const void* s2,
                        const void* s3, const void* s4, const void* s5,
                        const void* s6, ushort_t* __restrict__ dst) {
  long i = ((long)blockIdx.x * 256 + threadIdx.x) * 4;
  const void* src; long off;
  if      (i <  1572864) { src = s0; off = i; }
  else if (i <  3932160) { src = s1; off = i - 1572864; }
  else if (i <  6291456) { src = s2; off = i - 3932160; }
  else if (i <  8650752) { src = s3; off = i - 6291456; }
  else if (i < 11010048) { src = s4; off = i - 8650752; }
  else if (i < 15728640) { src = s5; off = i - 11010048; }
  else                   { src = s6; off = i - 15728640; }
  if (flags[0]) {  // already bf16: raw copy
    *(ushort4*)(dst + i) = *((const ushort4*)((const ushort_t*)src + off));
  } else {         // fp32 -> bf16
    float4 f = ((const float4*)src)[off >> 2];
    ushort4 o;
    o.x = f2bf(f.x); o.y = f2bf(f.y); o.z = f2bf(f.z); o.w = f2bf(f.w);
    *(ushort4*)(dst + i) = o;
  }
}

// biases -> fp32, concatenated [bs1|bs2|be1|be2|bo1|bo2] = 11520 floats
__global__ void cvt_bias(const int* __restrict__ flags,
                         const void* b0, const void* b1, const void* b2,
                         const void* b3, const void* b4, const void* b5,
                         float* __restrict__ dst) {
  int i = blockIdx.x * 256 + threadIdx.x;
  if (i >= 11520) return;
  const void* src; int off;
  if (i < 3072)       { src = b0; off = i; }
  else if (i < 3840)  { src = b1; off = i - 3072; }
  else if (i < 6912)  { src = b2; off = i - 3840; }
  else if (i < 7680)  { src = b3; off = i - 6912; }
  else if (i < 10752) { src = b4; off = i - 7680; }
  else                { src = b5; off = i - 10752; }
  dst[i] = flags[0] ? __bfloat162float(((const bf16*)src)[off])
                    : ((const float*)src)[off];
}

// C[M,N] = act(A[M,K] @ Bw[N,K]^T + bias), A optionally gathered from repS/repE.
// Dual-launch: blocks with blockIdx.x >= xsplit use {A2,Bw2,bias2,C2} (merged
// start/end branch launches). N is the per-half output width.
// LDS k-block XOR swizzle: LDS[row][kb] holds global k-block kb^((row>>1)&3);
// fragment reads invert it. Kills the 8-way ds_read_b128 bank conflict.
template <bool GATHER, bool RELU, bool OUTF32>
__global__ __launch_bounds__(256) void gemm_bt(
    const bf16* __restrict__ A, const bf16* __restrict__ A2,
    const bf16* __restrict__ repS, const bf16* __restrict__ repE,
    const int* __restrict__ sidx, int row_base,
    const bf16* __restrict__ Bw, const bf16* __restrict__ Bw2,
    const float* __restrict__ bias, const float* __restrict__ bias2,
    void* __restrict__ C, void* __restrict__ C2, int xsplit,
    int N, int Kdim) {
  __shared__ bf16 lA[BM * BK];  // 8 KB
  __shared__ bf16 lB[BN * BK];  // 8 KB

  const int tid  = threadIdx.x;
  const int lane = tid & 63;
  const int wave = tid >> 6;
  const int wm = wave >> 1, wn = wave & 1;  // 2x2 waves, each 64x64
  int bx = blockIdx.x;
  const bf16* Bw_ = Bw; const float* bias_ = bias; void* C_ = C; const bf16* A_ = A;
  if (bx >= xsplit) { bx -= xsplit; Bw_ = Bw2; bias_ = bias2; C_ = C2; A_ = A2; }
  const int m0 = blockIdx.y * BM;
  const int n0 = bx * BN;

  // staging: thread covers rows (tid>>2) and (tid>>2)+64; k-block XOR-swizzled.
  // swizzle value for row r is ((r>>1)&3); rows r and r+64 share it (64%8==0).
  const int srow = tid >> 2;
  const int scol = 8 * ((tid & 3) ^ ((tid >> 3) & 3));

  const bf16 *a0 = nullptr, *a1 = nullptr;
  const bf16 *pS0 = nullptr, *pE0 = nullptr, *pS1 = nullptr, *pE1 = nullptr;
  if (GATHER) {
    int r0 = row_base + m0 + srow;
    int r1 = r0 + 64;
    int b0 = r0 / 6144, b1 = r1 / 6144;
    int s0 = min(max(sidx[2 * r0], 0), 511);
    int e0 = min(max(sidx[2 * r0 + 1], 0), 511);
    int s1 = min(max(sidx[2 * r1], 0), 511);
    int e1 = min(max(sidx[2 * r1 + 1], 0), 511);
    pS0 = repS + ((size_t)b0 * 512 + s0) * 768 + scol;
    pE0 = repE + ((size_t)b0 * 512 + e0) * 768 + scol;
    pS1 = repS + ((size_t)b1 * 512 + s1) * 768 + scol;
    pE1 = repE + ((size_t)b1 * 512 + e1) * 768 + scol;
  } else {
    a0 = A_ + (size_t)(m0 + srow) * Kdim + scol;
    a1 = a0 + (size_t)64 * Kdim;
  }
  const bf16* b0p = Bw_ + (size_t)(n0 + srow) * Kdim + scol;
  const bf16* b1p = b0p + (size_t)64 * Kdim;

  f32x4 acc[4][4];
  const f32x4 z = {0.f, 0.f, 0.f, 0.f};
#pragma unroll
  for (int i = 0; i < 4; ++i)
#pragma unroll
    for (int j = 0; j < 4; ++j) acc[i][j] = z;

  const int fr = lane & 15;  // m (A) / n (B) within 16-tile
  // fragment k-block (lane>>4), un-swizzled for this lane's row parity:
  const int fk = 8 * ((lane >> 4) ^ ((lane >> 1) & 3));

  for (int k0 = 0; k0 < Kdim; k0 += BK) {
    const bf16 *sa0, *sa1;
    if (GATHER) {
      if (k0 < 768) { sa0 = pS0 + k0; sa1 = pS1 + k0; }
      else          { sa0 = pE0 + (k0 - 768); sa1 = pE1 + (k0 - 768); }
    } else {
      sa0 = a0 + k0; sa1 = a1 + k0;
    }
    gl_lds16(sa0, lA + tid * 8);
    gl_lds16(sa1, lA + 2048 + tid * 8);
    gl_lds16(b0p + k0, lB + tid * 8);
    gl_lds16(b1p + k0, lB + 2048 + tid * 8);
    __syncthreads();  // drains vmcnt -> LDS writes visible

    bf16x8 af[4], bv[4];
#pragma unroll
    for (int i = 0; i < 4; ++i)
      af[i] = *(const bf16x8*)(const void*)(lA + (wm * 64 + i * 16 + fr) * BK + fk);
#pragma unroll
    for (int j = 0; j < 4; ++j)
      bv[j] = *(const bf16x8*)(const void*)(lB + (wn * 64 + j * 16 + fr) * BK + fk);
#pragma unroll
    for (int i = 0; i < 4; ++i)
#pragma unroll
      for (int j = 0; j < 4; ++j)
        acc[i][j] = __builtin_amdgcn_mfma_f32_16x16x32_bf16(af[i], bv[j], acc[i][j], 0, 0, 0);
    __syncthreads();  // protect LDS before next stage
  }

  // epilogue: C/D layout col=lane&15 (n), row=(lane>>4)*4+reg (m)
  float* Cf = (float*)C_;
  bf16*  Cb = (bf16*)C_;
#pragma unroll
  for (int j = 0; j < 4; ++j) {
    int n = n0 + wn * 64 + j * 16 + fr;
    float bj = bias_[n];
#pragma unroll
    for (int i = 0; i < 4; ++i) {
      int mb = m0 + wm * 64 + i * 16 + (lane >> 4) * 4;
#pragma unroll
      for (int r = 0; r < 4; ++r) {
        float v = acc[i][j][r] + bj;
        if (RELU) v = fmaxf(v, 0.f);
        if (OUTF32) Cf[(size_t)(mb + r) * N + n] = v;
        else        Cb[(size_t)(mb + r) * N + n] = __float2bfloat16(v);
      }
    }
  }
}

extern "C" void kernel_launch(void* const* d_in, const int* in_sizes, int n_in,
                              void* d_out, int out_size, void* d_ws, size_t ws_size,
                              hipStream_t stream) {
  const void* h    = d_in[0];
  const void* sidx = d_in[1];
  const void *ws1 = d_in[2],  *bs1 = d_in[3];
  const void *ws2 = d_in[4],  *bs2 = d_in[5];
  const void *we1 = d_in[6],  *be1 = d_in[7];
  const void *we2 = d_in[8],  *be2 = d_in[9];
  const void *wo1 = d_in[10], *bo1 = d_in[11];
  const void *wo2 = d_in[12], *bo2 = d_in[13];

  // ---- workspace layout (bytes) ----
  char* p = (char*)d_ws;
  int*      flags = (int*)p;                 // 2 ints (+pad)
  int*      idx32 = (int*)(p + 256);         // 49152 ints
  float*    biasf = (float*)(p + 256 + 196608);            // 11520 f32 (pad)
  ushort_t* hb    = (ushort_t*)(p + 256 + 196608 + 49152); // contiguous bf16 region:
  ushort_t* w1sb  = hb   + (size_t)1572864;                //   h|w1s|w2s|w1e|w2e|wo1|wo2
  ushort_t* w2sb  = w1sb + (size_t)2359296;
  ushort_t* w1eb  = w2sb + (size_t)2359296;
  ushort_t* w2eb  = w1eb + (size_t)2359296;
  ushort_t* wo1b  = w2eb + (size_t)2359296;
  ushort_t* wo2b  = wo1b + (size_t)4718592;
  ushort_t* repS  = wo2b + (size_t)2359296;
  ushort_t* repE  = repS + (size_t)1572864;
  ushort_t* scr   = repE + (size_t)1572864;  // shared: phase A hidS|hidE, phase B hidO
  size_t fixed = (size_t)((char*)scr - (char*)d_ws);
  if (ws_size < fixed + (size_t)2 * 128 * 3072 * 2) return;  // clean failure
  size_t avail = ws_size - fixed;
  long long cT = (long long)(avail / ((size_t)2 * 3072 * 2));  // dual hid buffers
  cT = (cT / 128) * 128; if (cT > 2048) cT = 2048;
  long long cO = (long long)(avail / ((size_t)3072 * 2));
  cO = (cO / 128) * 128; if (cO > 24576) cO = 24576;
  if (cT < 128 || cO < 128) return;

  dim3 blk(256);
  const int XBIG = 0x40000000;
  // ---- dtype sniff + normalization (2 big + 2 tiny launches) ----
  sniff<<<1, blk, 0, stream>>>((const unsigned*)ws1, (const unsigned*)sidx, flags);
  norm_idx<<<192, blk, 0, stream>>>(flags, sidx, idx32);
  cvt_all<<<17664, blk, 0, stream>>>(flags, h, ws1, ws2, we1, we2, wo1, wo2, hb);
  cvt_bias<<<45, blk, 0, stream>>>(flags, bs1, bs2, be1, be2, bo1, bo2, biasf);
  const float *bs1f = biasf, *bs2f = biasf + 3072, *be1f = biasf + 3840,
              *be2f = biasf + 6912, *bo1f = biasf + 7680, *bo2f = biasf + 10752;

  // ---- Phase A: token MLPs -> repS, repE (start+end merged per launch) ----
  for (long long r = 0; r < 2048; r += cT) {
    long long mc = 2048 - r < cT ? 2048 - r : cT;
    ushort_t* hidS = scr;
    ushort_t* hidE = scr + (size_t)cT * 3072;
    gemm_bt<false, true, false><<<dim3(48, mc / 128), blk, 0, stream>>>(
        (const bf16*)hb + r * 768, (const bf16*)hb + r * 768,
        nullptr, nullptr, nullptr, 0,
        (const bf16*)w1sb, (const bf16*)w1eb, bs1f, be1f,
        hidS, hidE, 24, 3072, 768);
    gemm_bt<false, true, false><<<dim3(12, mc / 128), blk, 0, stream>>>(
        (const bf16*)hidS, (const bf16*)hidE,
        nullptr, nullptr, nullptr, 0,
        (const bf16*)w2sb, (const bf16*)w2eb, bs2f, be2f,
        (bf16*)repS + r * 768, (bf16*)repE + r * 768, 6, 768, 3072);
  }
  // ---- Phase B: output MLP over 24576 span rows; final GEMM writes fp32 ----
  float* outf = (float*)d_out;
  for (long long r = 0; r < 24576; r += cO) {
    long long mc = 24576 - r < cO ? 24576 - r : cO;
    gemm_bt<true, true, false><<<dim3(24, mc / 128), blk, 0, stream>>>(
        nullptr, nullptr, (const bf16*)repS, (const bf16*)repE, idx32, (int)r,
        (const bf16*)wo1b, nullptr, bo1f, nullptr,
        scr, nullptr, XBIG, 3072, 1536);
    gemm_bt<false, false, true><<<dim3(6, mc / 128), blk, 0, stream>>>(
        (const bf16*)scr, nullptr, nullptr, nullptr, nullptr, 0,
        (const bf16*)wo2b, nullptr, bo2f, nullptr,
        outf + (size_t)r * 768, nullptr, XBIG, 768, 3072);
  }
}

// Round 6
// 590.806 us; speedup vs baseline: 1.3549x; 1.1858x over previous
//
#include <hip/hip_runtime.h>
#include <hip/hip_bf16.h>

using bf16 = __hip_bfloat16;
using bf16x8 = __attribute__((ext_vector_type(8))) __bf16;
using f32x4  = __attribute__((ext_vector_type(4))) float;
typedef unsigned short ushort_t;

#define BM 128
#define BN 128
#define BK 32

// B=4, L=512, D=768, W=12, K_spans=6144, rows_out = B*K = 24576

__device__ __forceinline__ void gl_lds16(const void* g, void* l) {
  __builtin_amdgcn_global_load_lds(
      (const __attribute__((address_space(1))) void*)g,
      (__attribute__((address_space(3))) void*)l, 16, 0, 0);
}

__device__ __forceinline__ ushort_t f2bf(float f) {  // RNE fp32->bf16
  unsigned u = __float_as_uint(f);
  u += 0x7FFF + ((u >> 16) & 1);
  return (ushort_t)(u >> 16);
}

// flags[0]=1 if float inputs are stored as bf16 (else fp32)
// flags[1]=1 if span_idx is int64 (else int32)
__global__ void sniff(const unsigned* __restrict__ w1,
                      const unsigned* __restrict__ idx, int* flags) {
  __shared__ int cnt[2];
  if (threadIdx.x == 0) { cnt[0] = 0; cnt[1] = 0; }
  __syncthreads();
  int t = threadIdx.x;  // 256 threads
  int c0 = 0;
  for (int k = 0; k < 4; ++k) {
    unsigned lo = w1[t * 4 + k] & 0xFFFFu;
    unsigned e = (lo >> 7) & 0xFF;
    if (e <= 122) c0++;
  }
  int c1 = (idx[2 * t + 1] != 0) ? 1 : 0;
  atomicAdd(&cnt[0], c0);
  atomicAdd(&cnt[1], c1);
  __syncthreads();
  if (threadIdx.x == 0) {
    flags[0] = (cnt[0] >= 900) ? 1 : 0;
    flags[1] = (cnt[1] == 0) ? 1 : 0;
  }
}

__global__ void norm_idx(const int* __restrict__ flags, const void* __restrict__ src,
                         int* __restrict__ dst) {
  int i = blockIdx.x * 256 + threadIdx.x;  // grid covers exactly 49152
  int v = flags[1] ? (int)((const long long*)src)[i] : ((const int*)src)[i];
  dst[i] = v;
}

// One kernel converts h + all 6 weights into the contiguous bf16 region at dst.
__global__ void cvt_all(const int* __restrict__ flags,
                        const void* s0, const void* s1, const void* s2,
                        const void* s3, const void* s4, const void* s5,
                        const void* s6, ushort_t* __restrict__ dst) {
  long i = ((long)blockIdx.x * 256 + threadIdx.x) * 4;
  const void* src; long off;
  if      (i <  1572864) { src = s0; off = i; }
  else if (i <  3932160) { src = s1; off = i - 1572864; }
  else if (i <  6291456) { src = s2; off = i - 3932160; }
  else if (i <  8650752) { src = s3; off = i - 6291456; }
  else if (i < 11010048) { src = s4; off = i - 8650752; }
  else if (i < 15728640) { src = s5; off = i - 11010048; }
  else                   { src = s6; off = i - 15728640; }
  if (flags[0]) {
    *(ushort4*)(dst + i) = *((const ushort4*)((const ushort_t*)src + off));
  } else {
    float4 f = ((const float4*)src)[off >> 2];
    ushort4 o;
    o.x = f2bf(f.x); o.y = f2bf(f.y); o.z = f2bf(f.z); o.w = f2bf(f.w);
    *(ushort4*)(dst + i) = o;
  }
}

// biases -> fp32, [bs1|bs2|be1|be2|bo1|bo2|zeros] = 11520 + 3072 floats
__global__ void cvt_bias(const int* __restrict__ flags,
                         const void* b0, const void* b1, const void* b2,
                         const void* b3, const void* b4, const void* b5,
                         float* __restrict__ dst) {
  int i = blockIdx.x * 256 + threadIdx.x;
  if (i >= 14592) return;
  if (i >= 11520) { dst[i] = 0.f; return; }  // zero-bias tail
  const void* src; int off;
  if (i < 3072)       { src = b0; off = i; }
  else if (i < 3840)  { src = b1; off = i - 3072; }
  else if (i < 6912)  { src = b2; off = i - 3840; }
  else if (i < 7680)  { src = b3; off = i - 6912; }
  else if (i < 10752) { src = b4; off = i - 7680; }
  else                { src = b5; off = i - 10752; }
  dst[i] = flags[0] ? __bfloat162float(((const bf16*)src)[off])
                    : ((const float*)src)[off];
}

// C[M,N] = act(A[M,K] @ Bw[N,K(bstride)]^T + bias), A optionally gathered.
// Grid: (m-tiles, n-tiles) — m on blockIdx.x so same-A blocks (diff n) have
// linear ids differing by gridDim.x (mult of 8) -> same XCD -> A L2 reuse.
// Dual-launch: blocks with blockIdx.y >= nsplit use the second operand set.
// LDS k-block XOR swizzle kills the 8-way ds_read_b128 conflict.
template <bool GATHER, bool RELU, bool OUTF32>
__global__ __launch_bounds__(256) void gemm_bt(
    const bf16* __restrict__ A, const bf16* __restrict__ A2,
    const bf16* __restrict__ repS, const bf16* __restrict__ repE,
    const int* __restrict__ sidx, int row_base,
    const bf16* __restrict__ Bw, const bf16* __restrict__ Bw2,
    const float* __restrict__ bias, const float* __restrict__ bias2,
    void* __restrict__ C, void* __restrict__ C2, int nsplit,
    int N, int Kdim, int bstride) {
  __shared__ bf16 lA[BM * BK];
  __shared__ bf16 lB[BN * BK];

  const int tid  = threadIdx.x;
  const int lane = tid & 63;
  const int wave = tid >> 6;
  const int wm = wave >> 1, wn = wave & 1;
  int by = blockIdx.y;
  const bf16* Bw_ = Bw; const float* bias_ = bias; void* C_ = C; const bf16* A_ = A;
  if (by >= nsplit) { by -= nsplit; Bw_ = Bw2; bias_ = bias2; C_ = C2; A_ = A2; }
  const int m0 = blockIdx.x * BM;
  const int n0 = by * BN;

  const int srow = tid >> 2;
  const int scol = 8 * ((tid & 3) ^ ((tid >> 3) & 3));

  const bf16 *a0 = nullptr, *a1 = nullptr;
  const bf16 *pS0 = nullptr, *pE0 = nullptr, *pS1 = nullptr, *pE1 = nullptr;
  if (GATHER) {
    int r0 = row_base + m0 + srow;
    int r1 = r0 + 64;
    int b0 = r0 / 6144, b1 = r1 / 6144;
    int s0 = min(max(sidx[2 * r0], 0), 511);
    int e0 = min(max(sidx[2 * r0 + 1], 0), 511);
    int s1 = min(max(sidx[2 * r1], 0), 511);
    int e1 = min(max(sidx[2 * r1 + 1], 0), 511);
    pS0 = repS + ((size_t)b0 * 512 + s0) * 768 + scol;
    pE0 = repE + ((size_t)b0 * 512 + e0) * 768 + scol;
    pS1 = repS + ((size_t)b1 * 512 + s1) * 768 + scol;
    pE1 = repE + ((size_t)b1 * 512 + e1) * 768 + scol;
  } else {
    a0 = A_ + (size_t)(m0 + srow) * Kdim + scol;
    a1 = a0 + (size_t)64 * Kdim;
  }
  const bf16* b0p = Bw_ + (size_t)(n0 + srow) * bstride + scol;
  const bf16* b1p = b0p + (size_t)64 * bstride;

  f32x4 acc[4][4];
  const f32x4 z = {0.f, 0.f, 0.f, 0.f};
#pragma unroll
  for (int i = 0; i < 4; ++i)
#pragma unroll
    for (int j = 0; j < 4; ++j) acc[i][j] = z;

  const int fr = lane & 15;
  const int fk = 8 * ((lane >> 4) ^ ((lane >> 1) & 3));

  for (int k0 = 0; k0 < Kdim; k0 += BK) {
    const bf16 *sa0, *sa1;
    if (GATHER) {
      if (k0 < 768) { sa0 = pS0 + k0; sa1 = pS1 + k0; }
      else          { sa0 = pE0 + (k0 - 768); sa1 = pE1 + (k0 - 768); }
    } else {
      sa0 = a0 + k0; sa1 = a1 + k0;
    }
    gl_lds16(sa0, lA + tid * 8);
    gl_lds16(sa1, lA + 2048 + tid * 8);
    gl_lds16(b0p + k0, lB + tid * 8);
    gl_lds16(b1p + k0, lB + 2048 + tid * 8);
    __syncthreads();

    bf16x8 af[4], bv[4];
#pragma unroll
    for (int i = 0; i < 4; ++i)
      af[i] = *(const bf16x8*)(const void*)(lA + (wm * 64 + i * 16 + fr) * BK + fk);
#pragma unroll
    for (int j = 0; j < 4; ++j)
      bv[j] = *(const bf16x8*)(const void*)(lB + (wn * 64 + j * 16 + fr) * BK + fk);
#pragma unroll
    for (int i = 0; i < 4; ++i)
#pragma unroll
      for (int j = 0; j < 4; ++j)
        acc[i][j] = __builtin_amdgcn_mfma_f32_16x16x32_bf16(af[i], bv[j], acc[i][j], 0, 0, 0);
    __syncthreads();
  }

  float* Cf = (float*)C_;
  bf16*  Cb = (bf16*)C_;
#pragma unroll
  for (int j = 0; j < 4; ++j) {
    int n = n0 + wn * 64 + j * 16 + fr;
    float bj = bias_[n];
#pragma unroll
    for (int i = 0; i < 4; ++i) {
      int mb = m0 + wm * 64 + i * 16 + (lane >> 4) * 4;
#pragma unroll
      for (int r = 0; r < 4; ++r) {
        float v = acc[i][j][r] + bj;
        if (RELU) v = fmaxf(v, 0.f);
        if (OUTF32) Cf[(size_t)(mb + r) * N + n] = v;
        else        Cb[(size_t)(mb + r) * N + n] = __float2bfloat16(v);
      }
    }
  }
}

// Final GEMM with fused gather-add-relu A-staging:
//   A[r][k] = relu(Ps[tok_s(r)][k] + Pe[tok_e(r)][k]),  out = A @ wo2^T + bo2
// Ps/Pe are [2048][3072], fp32 (PF32) or bf16. N=768, K=3072. Grid (192, 6).
template <bool PF32>
__global__ __launch_bounds__(256) void gemm_final_fused(
    const void* __restrict__ Ps, const void* __restrict__ Pe,
    const int* __restrict__ sidx,
    const bf16* __restrict__ Bw, const float* __restrict__ bias,
    float* __restrict__ out) {
  __shared__ bf16 lA[BM * BK];
  __shared__ bf16 lB[BN * BK];

  const int tid  = threadIdx.x;
  const int lane = tid & 63;
  const int wave = tid >> 6;
  const int wm = wave >> 1, wn = wave & 1;
  const int m0 = blockIdx.x * BM;
  const int n0 = blockIdx.y * BN;

  const int srow = tid >> 2;
  const int scol = 8 * ((tid & 3) ^ ((tid >> 3) & 3));

  int r0 = m0 + srow, r1 = r0 + 64;
  int b0 = r0 / 6144, b1 = r1 / 6144;
  int s0 = min(max(sidx[2 * r0], 0), 511);
  int e0 = min(max(sidx[2 * r0 + 1], 0), 511);
  int s1 = min(max(sidx[2 * r1], 0), 511);
  int e1 = min(max(sidx[2 * r1 + 1], 0), 511);
  size_t os0 = ((size_t)b0 * 512 + s0) * 3072 + scol;
  size_t oe0 = ((size_t)b0 * 512 + e0) * 3072 + scol;
  size_t os1 = ((size_t)b1 * 512 + s1) * 3072 + scol;
  size_t oe1 = ((size_t)b1 * 512 + e1) * 3072 + scol;

  const bf16* bp0 = Bw + (size_t)(n0 + srow) * 3072 + scol;
  const bf16* bp1 = bp0 + (size_t)64 * 3072;

  f32x4 acc[4][4];
  const f32x4 z = {0.f, 0.f, 0.f, 0.f};
#pragma unroll
  for (int i = 0; i < 4; ++i)
#pragma unroll
    for (int j = 0; j < 4; ++j) acc[i][j] = z;

  const int fr = lane & 15;
  const int fk = 8 * ((lane >> 4) ^ ((lane >> 1) & 3));

  for (int k0 = 0; k0 < 3072; k0 += BK) {
    gl_lds16(bp0 + k0, lB + tid * 8);
    gl_lds16(bp1 + k0, lB + 2048 + tid * 8);
    // A rows: gather + add + relu + pack, written via LDS
#pragma unroll
    for (int h = 0; h < 2; ++h) {
      size_t osS = h ? os1 : os0;
      size_t osE = h ? oe1 : oe0;
      float v[8];
      if (PF32) {
        const float* fS = (const float*)Ps + osS + k0;
        const float* fE = (const float*)Pe + osE + k0;
        float4 xa = *(const float4*)fS, xb = *(const float4*)(fS + 4);
        float4 ya = *(const float4*)fE, yb = *(const float4*)(fE + 4);
        v[0] = xa.x + ya.x; v[1] = xa.y + ya.y; v[2] = xa.z + ya.z; v[3] = xa.w + ya.w;
        v[4] = xb.x + yb.x; v[5] = xb.y + yb.y; v[6] = xb.z + yb.z; v[7] = xb.w + yb.w;
      } else {
        const ushort_t* fS = (const ushort_t*)Ps + osS + k0;
        const ushort_t* fE = (const ushort_t*)Pe + osE + k0;
        ushort4 xa = *(const ushort4*)fS, xb = *(const ushort4*)(fS + 4);
        ushort4 ya = *(const ushort4*)fE, yb = *(const ushort4*)(fE + 4);
        v[0] = __uint_as_float((unsigned)xa.x << 16) + __uint_as_float((unsigned)ya.x << 16);
        v[1] = __uint_as_float((unsigned)xa.y << 16) + __uint_as_float((unsigned)ya.y << 16);
        v[2] = __uint_as_float((unsigned)xa.z << 16) + __uint_as_float((unsigned)ya.z << 16);
        v[3] = __uint_as_float((unsigned)xa.w << 16) + __uint_as_float((unsigned)ya.w << 16);
        v[4] = __uint_as_float((unsigned)xb.x << 16) + __uint_as_float((unsigned)yb.x << 16);
        v[5] = __uint_as_float((unsigned)xb.y << 16) + __uint_as_float((unsigned)yb.y << 16);
        v[6] = __uint_as_float((unsigned)xb.z << 16) + __uint_as_float((unsigned)yb.z << 16);
        v[7] = __uint_as_float((unsigned)xb.w << 16) + __uint_as_float((unsigned)yb.w << 16);
      }
      ushort4 lo, hi;
      lo.x = f2bf(fmaxf(v[0], 0.f)); lo.y = f2bf(fmaxf(v[1], 0.f));
      lo.z = f2bf(fmaxf(v[2], 0.f)); lo.w = f2bf(fmaxf(v[3], 0.f));
      hi.x = f2bf(fmaxf(v[4], 0.f)); hi.y = f2bf(fmaxf(v[5], 0.f));
      hi.z = f2bf(fmaxf(v[6], 0.f)); hi.w = f2bf(fmaxf(v[7], 0.f));
      ushort_t* dst = (ushort_t*)(lA + h * 2048 + tid * 8);
      *(ushort4*)dst = lo;
      *(ushort4*)(dst + 4) = hi;
    }
    __syncthreads();

    bf16x8 af[4], bv[4];
#pragma unroll
    for (int i = 0; i < 4; ++i)
      af[i] = *(const bf16x8*)(const void*)(lA + (wm * 64 + i * 16 + fr) * BK + fk);
#pragma unroll
    for (int j = 0; j < 4; ++j)
      bv[j] = *(const bf16x8*)(const void*)(lB + (wn * 64 + j * 16 + fr) * BK + fk);
#pragma unroll
    for (int i = 0; i < 4; ++i)
#pragma unroll
      for (int j = 0; j < 4; ++j)
        acc[i][j] = __builtin_amdgcn_mfma_f32_16x16x32_bf16(af[i], bv[j], acc[i][j], 0, 0, 0);
    __syncthreads();
  }

#pragma unroll
  for (int j = 0; j < 4; ++j) {
    int n = n0 + wn * 64 + j * 16 + fr;
    float bj = bias[n];
#pragma unroll
    for (int i = 0; i < 4; ++i) {
      int mb = m0 + wm * 64 + i * 16 + (lane >> 4) * 4;
#pragma unroll
      for (int r = 0; r < 4; ++r)
        out[(size_t)(mb + r) * 768 + n] = acc[i][j][r] + bj;
    }
  }
}

extern "C" void kernel_launch(void* const* d_in, const int* in_sizes, int n_in,
                              void* d_out, int out_size, void* d_ws, size_t ws_size,
                              hipStream_t stream) {
  const void* h    = d_in[0];
  const void* sidx = d_in[1];
  const void *ws1 = d_in[2],  *bs1 = d_in[3];
  const void *ws2 = d_in[4],  *bs2 = d_in[5];
  const void *we1 = d_in[6],  *be1 = d_in[7];
  const void *we2 = d_in[8],  *be2 = d_in[9];
  const void *wo1 = d_in[10], *bo1 = d_in[11];
  const void *wo2 = d_in[12], *bo2 = d_in[13];

  // ---- fixed workspace region ----
  char* p = (char*)d_ws;
  int*      flags = (int*)p;
  int*      idx32 = (int*)(p + 256);
  float*    biasf = (float*)(p + 256 + 196608);            // 14592 f32 (incl zeros)
  ushort_t* hb    = (ushort_t*)(p + 256 + 196608 + 65536);
  ushort_t* w1sb  = hb   + (size_t)1572864;
  ushort_t* w2sb  = w1sb + (size_t)2359296;
  ushort_t* w1eb  = w2sb + (size_t)2359296;
  ushort_t* w2eb  = w1eb + (size_t)2359296;
  ushort_t* wo1b  = w2eb + (size_t)2359296;
  ushort_t* wo2b  = wo1b + (size_t)4718592;
  ushort_t* repS  = wo2b + (size_t)2359296;
  ushort_t* repE  = repS + (size_t)1572864;
  char*     R     = (char*)(repE + (size_t)1572864);  // transient region
  size_t fixed = (size_t)(R - (char*)d_ws);
  if (ws_size < fixed) return;
  size_t Rsz = ws_size - fixed;

  const size_t P_F32 = (size_t)2 * 2048 * 3072 * 4;  // Ps+Pe fp32
  const size_t P_BF  = (size_t)2 * 2048 * 3072 * 2;  // Ps+Pe bf16 (== phase-A hid)
  int tier = (Rsz >= P_F32) ? 1 : (Rsz >= P_BF) ? 2 : 3;

  dim3 blk(256);
  const int XBIG = 0x40000000;
  sniff<<<1, blk, 0, stream>>>((const unsigned*)ws1, (const unsigned*)sidx, flags);
  norm_idx<<<192, blk, 0, stream>>>(flags, sidx, idx32);
  cvt_all<<<17664, blk, 0, stream>>>(flags, h, ws1, ws2, we1, we2, wo1, wo2, hb);
  cvt_bias<<<57, blk, 0, stream>>>(flags, bs1, bs2, be1, be2, bo1, bo2, biasf);
  const float *bs1f = biasf, *bs2f = biasf + 3072, *be1f = biasf + 3840,
              *be2f = biasf + 6912, *bo1f = biasf + 7680, *bo2f = biasf + 10752,
              *zerof = biasf + 11520;
  float* outf = (float*)d_out;

  if (tier <= 2) {
    // Phase A: token MLPs (start+end merged), hid scratch in R (dead after)
    ushort_t* hidS = (ushort_t*)R;
    ushort_t* hidE = hidS + (size_t)2048 * 3072;
    gemm_bt<false, true, false><<<dim3(16, 48), blk, 0, stream>>>(
        (const bf16*)hb, (const bf16*)hb, nullptr, nullptr, nullptr, 0,
        (const bf16*)w1sb, (const bf16*)w1eb, bs1f, be1f,
        hidS, hidE, 24, 3072, 768, 768);
    gemm_bt<false, true, false><<<dim3(16, 12), blk, 0, stream>>>(
        (const bf16*)hidS, (const bf16*)hidE, nullptr, nullptr, nullptr, 0,
        (const bf16*)w2sb, (const bf16*)w2eb, bs2f, be2f,
        (bf16*)repS, (bf16*)repE, 6, 768, 3072, 3072);
    // Phase B': P_s = repS@wo1[:, :768]^T + bo1 ; P_e = repE@wo1[:, 768:]^T
    void* Ps = R;
    void* Pe = (char*)R + (tier == 1 ? (size_t)2048 * 3072 * 4 : (size_t)2048 * 3072 * 2);
    if (tier == 1) {
      gemm_bt<false, false, true><<<dim3(16, 48), blk, 0, stream>>>(
          (const bf16*)repS, (const bf16*)repE, nullptr, nullptr, nullptr, 0,
          (const bf16*)wo1b, (const bf16*)wo1b + 768, bo1f, zerof,
          Ps, Pe, 24, 3072, 768, 1536);
      gemm_final_fused<true><<<dim3(192, 6), blk, 0, stream>>>(
          Ps, Pe, idx32, (const bf16*)wo2b, bo2f, outf);
    } else {
      gemm_bt<false, false, false><<<dim3(16, 48), blk, 0, stream>>>(
          (const bf16*)repS, (const bf16*)repE, nullptr, nullptr, nullptr, 0,
          (const bf16*)wo1b, (const bf16*)wo1b + 768, bo1f, zerof,
          Ps, Pe, 24, 3072, 768, 1536);
      gemm_final_fused<false><<<dim3(192, 6), blk, 0, stream>>>(
          Ps, Pe, idx32, (const bf16*)wo2b, bo2f, outf);
    }
  } else {
    // Tier 3 fallback: round-5 two-pass path, chunked in R
    long long cT = (long long)(Rsz / ((size_t)2 * 3072 * 2));
    cT = (cT / 128) * 128; if (cT > 2048) cT = 2048;
    long long cO = (long long)(Rsz / ((size_t)3072 * 2));
    cO = (cO / 128) * 128; if (cO > 24576) cO = 24576;
    if (cT < 128 || cO < 128) return;
    ushort_t* scr = (ushort_t*)R;
    for (long long r = 0; r < 2048; r += cT) {
      long long mc = 2048 - r < cT ? 2048 - r : cT;
      ushort_t* hidS = scr;
      ushort_t* hidE = scr + (size_t)cT * 3072;
      gemm_bt<false, true, false><<<dim3(mc / 128, 48), blk, 0, stream>>>(
          (const bf16*)hb + r * 768, (const bf16*)hb + r * 768,
          nullptr, nullptr, nullptr, 0,
          (const bf16*)w1sb, (const bf16*)w1eb, bs1f, be1f,
          hidS, hidE, 24, 3072, 768, 768);
      gemm_bt<false, true, false><<<dim3(mc / 128, 12), blk, 0, stream>>>(
          (const bf16*)hidS, (const bf16*)hidE, nullptr, nullptr, nullptr, 0,
          (const bf16*)w2sb, (const bf16*)w2eb, bs2f, be2f,
          (bf16*)repS + r * 768, (bf16*)repE + r * 768, 6, 768, 3072, 3072);
    }
    for (long long r = 0; r < 24576; r += cO) {
      long long mc = 24576 - r < cO ? 24576 - r : cO;
      gemm_bt<true, true, false><<<dim3(mc / 128, 24), blk, 0, stream>>>(
          nullptr, nullptr, (const bf16*)repS, (const bf16*)repE, idx32, (int)r,
          (const bf16*)wo1b, nullptr, bo1f, nullptr,
          scr, nullptr, XBIG, 3072, 1536, 1536);
      gemm_bt<false, false, true><<<dim3(mc / 128, 6), blk, 0, stream>>>(
          (const bf16*)scr, nullptr, nullptr, nullptr, nullptr, 0,
          (const bf16*)wo2b, nullptr, bo2f, nullptr,
          outf + (size_t)r * 768, nullptr, XBIG, 768, 3072, 3072);
    }
  }
}

// Round 7
// 585.450 us; speedup vs baseline: 1.3673x; 1.0091x over previous
//
#include <hip/hip_runtime.h>
#include <hip/hip_bf16.h>

using bf16 = __hip_bfloat16;
using bf16x8 = __attribute__((ext_vector_type(8))) __bf16;
using f32x4  = __attribute__((ext_vector_type(4))) float;
typedef unsigned short ushort_t;

#define BM 128
#define BN 128
#define BK 32

// B=4, L=512, D=768, W=12, K_spans=6144, rows_out = B*K = 24576

__device__ __forceinline__ void gl_lds16(const void* g, void* l) {
  __builtin_amdgcn_global_load_lds(
      (const __attribute__((address_space(1))) void*)g,
      (__attribute__((address_space(3))) void*)l, 16, 0, 0);
}

__device__ __forceinline__ ushort_t f2bf(float f) {  // RNE fp32->bf16
  unsigned u = __float_as_uint(f);
  u += 0x7FFF + ((u >> 16) & 1);
  return (ushort_t)(u >> 16);
}

// flags[0]=1 if float inputs are stored as bf16 (else fp32)
// flags[1]=1 if span_idx is int64 (else int32)
__global__ void sniff(const unsigned* __restrict__ w1,
                      const unsigned* __restrict__ idx, int* flags) {
  __shared__ int cnt[2];
  if (threadIdx.x == 0) { cnt[0] = 0; cnt[1] = 0; }
  __syncthreads();
  int t = threadIdx.x;  // 256 threads
  int c0 = 0;
  for (int k = 0; k < 4; ++k) {
    unsigned lo = w1[t * 4 + k] & 0xFFFFu;
    unsigned e = (lo >> 7) & 0xFF;
    if (e <= 122) c0++;
  }
  int c1 = (idx[2 * t + 1] != 0) ? 1 : 0;
  atomicAdd(&cnt[0], c0);
  atomicAdd(&cnt[1], c1);
  __syncthreads();
  if (threadIdx.x == 0) {
    flags[0] = (cnt[0] >= 900) ? 1 : 0;
    flags[1] = (cnt[1] == 0) ? 1 : 0;
  }
}

__global__ void norm_idx(const int* __restrict__ flags, const void* __restrict__ src,
                         int* __restrict__ dst) {
  int i = blockIdx.x * 256 + threadIdx.x;  // grid covers exactly 49152
  int v = flags[1] ? (int)((const long long*)src)[i] : ((const int*)src)[i];
  dst[i] = v;
}

// One kernel converts h + all 6 weights into the contiguous bf16 region at dst.
__global__ void cvt_all(const int* __restrict__ flags,
                        const void* s0, const void* s1, const void* s2,
                        const void* s3, const void* s4, const void* s5,
                        const void* s6, ushort_t* __restrict__ dst) {
  long i = ((long)blockIdx.x * 256 + threadIdx.x) * 4;
  const void* src; long off;
  if      (i <  1572864) { src = s0; off = i; }
  else if (i <  3932160) { src = s1; off = i - 1572864; }
  else if (i <  6291456) { src = s2; off = i - 3932160; }
  else if (i <  8650752) { src = s3; off = i - 6291456; }
  else if (i < 11010048) { src = s4; off = i - 8650752; }
  else if (i < 15728640) { src = s5; off = i - 11010048; }
  else                   { src = s6; off = i - 15728640; }
  if (flags[0]) {
    *(ushort4*)(dst + i) = *((const ushort4*)((const ushort_t*)src + off));
  } else {
    float4 f = ((const float4*)src)[off >> 2];
    ushort4 o;
    o.x = f2bf(f.x); o.y = f2bf(f.y); o.z = f2bf(f.z); o.w = f2bf(f.w);
    *(ushort4*)(dst + i) = o;
  }
}

// biases -> fp32, [bs1|bs2|be1|be2|bo1|bo2|zeros] = 11520 + 3072 floats
__global__ void cvt_bias(const int* __restrict__ flags,
                         const void* b0, const void* b1, const void* b2,
                         const void* b3, const void* b4, const void* b5,
                         float* __restrict__ dst) {
  int i = blockIdx.x * 256 + threadIdx.x;
  if (i >= 14592) return;
  if (i >= 11520) { dst[i] = 0.f; return; }  // zero-bias tail
  const void* src; int off;
  if (i < 3072)       { src = b0; off = i; }
  else if (i < 3840)  { src = b1; off = i - 3072; }
  else if (i < 6912)  { src = b2; off = i - 3840; }
  else if (i < 7680)  { src = b3; off = i - 6912; }
  else if (i < 10752) { src = b4; off = i - 7680; }
  else                { src = b5; off = i - 10752; }
  dst[i] = flags[0] ? __bfloat162float(((const bf16*)src)[off])
                    : ((const float*)src)[off];
}

// C[M,N] = act(A[M,K] @ Bw[N,K(bstride)]^T + bias), A optionally gathered.
// Grid: (m-tiles, n-tiles) — m on blockIdx.x so same-A blocks (diff n) have
// linear ids differing by gridDim.x (mult of 8) -> same XCD -> A L2 reuse.
// Dual-launch: blocks with blockIdx.y >= nsplit use the second operand set.
// LDS k-block XOR swizzle kills the 8-way ds_read_b128 conflict.
template <bool GATHER, bool RELU, bool OUTF32>
__global__ __launch_bounds__(256) void gemm_bt(
    const bf16* __restrict__ A, const bf16* __restrict__ A2,
    const bf16* __restrict__ repS, const bf16* __restrict__ repE,
    const int* __restrict__ sidx, int row_base,
    const bf16* __restrict__ Bw, const bf16* __restrict__ Bw2,
    const float* __restrict__ bias, const float* __restrict__ bias2,
    void* __restrict__ C, void* __restrict__ C2, int nsplit,
    int N, int Kdim, int bstride) {
  __shared__ bf16 lA[BM * BK];
  __shared__ bf16 lB[BN * BK];

  const int tid  = threadIdx.x;
  const int lane = tid & 63;
  const int wave = tid >> 6;
  const int wm = wave >> 1, wn = wave & 1;
  int by = blockIdx.y;
  const bf16* Bw_ = Bw; const float* bias_ = bias; void* C_ = C; const bf16* A_ = A;
  if (by >= nsplit) { by -= nsplit; Bw_ = Bw2; bias_ = bias2; C_ = C2; A_ = A2; }
  const int m0 = blockIdx.x * BM;
  const int n0 = by * BN;

  const int srow = tid >> 2;
  const int scol = 8 * ((tid & 3) ^ ((tid >> 3) & 3));

  const bf16 *a0 = nullptr, *a1 = nullptr;
  const bf16 *pS0 = nullptr, *pE0 = nullptr, *pS1 = nullptr, *pE1 = nullptr;
  if (GATHER) {
    int r0 = row_base + m0 + srow;
    int r1 = r0 + 64;
    int b0 = r0 / 6144, b1 = r1 / 6144;
    int s0 = min(max(sidx[2 * r0], 0), 511);
    int e0 = min(max(sidx[2 * r0 + 1], 0), 511);
    int s1 = min(max(sidx[2 * r1], 0), 511);
    int e1 = min(max(sidx[2 * r1 + 1], 0), 511);
    pS0 = repS + ((size_t)b0 * 512 + s0) * 768 + scol;
    pE0 = repE + ((size_t)b0 * 512 + e0) * 768 + scol;
    pS1 = repS + ((size_t)b1 * 512 + s1) * 768 + scol;
    pE1 = repE + ((size_t)b1 * 512 + e1) * 768 + scol;
  } else {
    a0 = A_ + (size_t)(m0 + srow) * Kdim + scol;
    a1 = a0 + (size_t)64 * Kdim;
  }
  const bf16* b0p = Bw_ + (size_t)(n0 + srow) * bstride + scol;
  const bf16* b1p = b0p + (size_t)64 * bstride;

  f32x4 acc[4][4];
  const f32x4 z = {0.f, 0.f, 0.f, 0.f};
#pragma unroll
  for (int i = 0; i < 4; ++i)
#pragma unroll
    for (int j = 0; j < 4; ++j) acc[i][j] = z;

  const int fr = lane & 15;
  const int fk = 8 * ((lane >> 4) ^ ((lane >> 1) & 3));

  for (int k0 = 0; k0 < Kdim; k0 += BK) {
    const bf16 *sa0, *sa1;
    if (GATHER) {
      if (k0 < 768) { sa0 = pS0 + k0; sa1 = pS1 + k0; }
      else          { sa0 = pE0 + (k0 - 768); sa1 = pE1 + (k0 - 768); }
    } else {
      sa0 = a0 + k0; sa1 = a1 + k0;
    }
    gl_lds16(sa0, lA + tid * 8);
    gl_lds16(sa1, lA + 2048 + tid * 8);
    gl_lds16(b0p + k0, lB + tid * 8);
    gl_lds16(b1p + k0, lB + 2048 + tid * 8);
    __syncthreads();

    bf16x8 af[4], bv[4];
#pragma unroll
    for (int i = 0; i < 4; ++i)
      af[i] = *(const bf16x8*)(const void*)(lA + (wm * 64 + i * 16 + fr) * BK + fk);
#pragma unroll
    for (int j = 0; j < 4; ++j)
      bv[j] = *(const bf16x8*)(const void*)(lB + (wn * 64 + j * 16 + fr) * BK + fk);
#pragma unroll
    for (int i = 0; i < 4; ++i)
#pragma unroll
      for (int j = 0; j < 4; ++j)
        acc[i][j] = __builtin_amdgcn_mfma_f32_16x16x32_bf16(af[i], bv[j], acc[i][j], 0, 0, 0);
    __syncthreads();
  }

  float* Cf = (float*)C_;
  bf16*  Cb = (bf16*)C_;
#pragma unroll
  for (int j = 0; j < 4; ++j) {
    int n = n0 + wn * 64 + j * 16 + fr;
    float bj = bias_[n];
#pragma unroll
    for (int i = 0; i < 4; ++i) {
      int mb = m0 + wm * 64 + i * 16 + (lane >> 4) * 4;
#pragma unroll
      for (int r = 0; r < 4; ++r) {
        float v = acc[i][j][r] + bj;
        if (RELU) v = fmaxf(v, 0.f);
        if (OUTF32) Cf[(size_t)(mb + r) * N + n] = v;
        else        Cb[(size_t)(mb + r) * N + n] = __float2bfloat16(v);
      }
    }
  }
}

// Final GEMM with fused gather-add-relu A-staging (bf16 P):
//   A[r][k] = relu(Ps[tok_s(r)][k] + Pe[tok_e(r)][k]),  out = A @ wo2^T + bo2
// Ps/Pe are [2048][3072] bf16. N=768, K=3072. Grid (192, 6).
__global__ __launch_bounds__(256) void gemm_final_fused(
    const ushort_t* __restrict__ Ps, const ushort_t* __restrict__ Pe,
    const int* __restrict__ sidx,
    const bf16* __restrict__ Bw, const float* __restrict__ bias,
    float* __restrict__ out) {
  __shared__ bf16 lA[BM * BK];
  __shared__ bf16 lB[BN * BK];

  const int tid  = threadIdx.x;
  const int lane = tid & 63;
  const int wave = tid >> 6;
  const int wm = wave >> 1, wn = wave & 1;
  const int m0 = blockIdx.x * BM;
  const int n0 = blockIdx.y * BN;

  const int srow = tid >> 2;
  const int scol = 8 * ((tid & 3) ^ ((tid >> 3) & 3));

  int r0 = m0 + srow, r1 = r0 + 64;
  int b0 = r0 / 6144, b1 = r1 / 6144;
  int s0 = min(max(sidx[2 * r0], 0), 511);
  int e0 = min(max(sidx[2 * r0 + 1], 0), 511);
  int s1 = min(max(sidx[2 * r1], 0), 511);
  int e1 = min(max(sidx[2 * r1 + 1], 0), 511);
  const ushort_t* pS0 = Ps + ((size_t)b0 * 512 + s0) * 3072 + scol;
  const ushort_t* pE0 = Pe + ((size_t)b0 * 512 + e0) * 3072 + scol;
  const ushort_t* pS1 = Ps + ((size_t)b1 * 512 + s1) * 3072 + scol;
  const ushort_t* pE1 = Pe + ((size_t)b1 * 512 + e1) * 3072 + scol;

  const bf16* bp0 = Bw + (size_t)(n0 + srow) * 3072 + scol;
  const bf16* bp1 = bp0 + (size_t)64 * 3072;

  f32x4 acc[4][4];
  const f32x4 z = {0.f, 0.f, 0.f, 0.f};
#pragma unroll
  for (int i = 0; i < 4; ++i)
#pragma unroll
    for (int j = 0; j < 4; ++j) acc[i][j] = z;

  const int fr = lane & 15;
  const int fk = 8 * ((lane >> 4) ^ ((lane >> 1) & 3));

  for (int k0 = 0; k0 < 3072; k0 += BK) {
    gl_lds16(bp0 + k0, lB + tid * 8);
    gl_lds16(bp1 + k0, lB + 2048 + tid * 8);
    // A rows: 16B bf16 gathers + packed add + relu + pack, written via LDS
#pragma unroll
    for (int h = 0; h < 2; ++h) {
      uint4 xs = *(const uint4*)(const void*)((h ? pS1 : pS0) + k0);
      uint4 xe = *(const uint4*)(const void*)((h ? pE1 : pE0) + k0);
      unsigned w[4];
      const unsigned* us = &xs.x;
      const unsigned* ue = &xe.x;
#pragma unroll
      for (int q = 0; q < 4; ++q) {
        float lo = __uint_as_float(us[q] << 16) + __uint_as_float(ue[q] << 16);
        float hi = __uint_as_float(us[q] & 0xFFFF0000u) +
                   __uint_as_float(ue[q] & 0xFFFF0000u);
        w[q] = (unsigned)f2bf(fmaxf(lo, 0.f)) |
               ((unsigned)f2bf(fmaxf(hi, 0.f)) << 16);
      }
      *(uint4*)(void*)(lA + h * 2048 + tid * 8) = *(const uint4*)w;
    }
    __syncthreads();

    bf16x8 af[4], bv[4];
#pragma unroll
    for (int i = 0; i < 4; ++i)
      af[i] = *(const bf16x8*)(const void*)(lA + (wm * 64 + i * 16 + fr) * BK + fk);
#pragma unroll
    for (int j = 0; j < 4; ++j)
      bv[j] = *(const bf16x8*)(const void*)(lB + (wn * 64 + j * 16 + fr) * BK + fk);
#pragma unroll
    for (int i = 0; i < 4; ++i)
#pragma unroll
      for (int j = 0; j < 4; ++j)
        acc[i][j] = __builtin_amdgcn_mfma_f32_16x16x32_bf16(af[i], bv[j], acc[i][j], 0, 0, 0);
    __syncthreads();
  }

#pragma unroll
  for (int j = 0; j < 4; ++j) {
    int n = n0 + wn * 64 + j * 16 + fr;
    float bj = bias[n];
#pragma unroll
    for (int i = 0; i < 4; ++i) {
      int mb = m0 + wm * 64 + i * 16 + (lane >> 4) * 4;
#pragma unroll
      for (int r = 0; r < 4; ++r)
        out[(size_t)(mb + r) * 768 + n] = acc[i][j][r] + bj;
    }
  }
}

extern "C" void kernel_launch(void* const* d_in, const int* in_sizes, int n_in,
                              void* d_out, int out_size, void* d_ws, size_t ws_size,
                              hipStream_t stream) {
  const void* h    = d_in[0];
  const void* sidx = d_in[1];
  const void *ws1 = d_in[2],  *bs1 = d_in[3];
  const void *ws2 = d_in[4],  *bs2 = d_in[5];
  const void *we1 = d_in[6],  *be1 = d_in[7];
  const void *we2 = d_in[8],  *be2 = d_in[9];
  const void *wo1 = d_in[10], *bo1 = d_in[11];
  const void *wo2 = d_in[12], *bo2 = d_in[13];

  // ---- fixed workspace region ----
  char* p = (char*)d_ws;
  int*      flags = (int*)p;
  int*      idx32 = (int*)(p + 256);
  float*    biasf = (float*)(p + 256 + 196608);            // 14592 f32 (incl zeros)
  ushort_t* hb    = (ushort_t*)(p + 256 + 196608 + 65536);
  ushort_t* w1sb  = hb   + (size_t)1572864;
  ushort_t* w2sb  = w1sb + (size_t)2359296;
  ushort_t* w1eb  = w2sb + (size_t)2359296;
  ushort_t* w2eb  = w1eb + (size_t)2359296;
  ushort_t* wo1b  = w2eb + (size_t)2359296;
  ushort_t* wo2b  = wo1b + (size_t)4718592;
  ushort_t* repS  = wo2b + (size_t)2359296;
  ushort_t* repE  = repS + (size_t)1572864;
  char*     R     = (char*)(repE + (size_t)1572864);  // transient region
  size_t fixed = (size_t)(R - (char*)d_ws);
  if (ws_size < fixed) return;
  size_t Rsz = ws_size - fixed;

  const size_t P_BF = (size_t)2 * 2048 * 3072 * 2;  // Ps+Pe bf16 (== phase-A hid)
  int tier = (Rsz >= P_BF) ? 2 : 3;

  dim3 blk(256);
  const int XBIG = 0x40000000;
  sniff<<<1, blk, 0, stream>>>((const unsigned*)ws1, (const unsigned*)sidx, flags);
  norm_idx<<<192, blk, 0, stream>>>(flags, sidx, idx32);
  cvt_all<<<17664, blk, 0, stream>>>(flags, h, ws1, ws2, we1, we2, wo1, wo2, hb);
  cvt_bias<<<57, blk, 0, stream>>>(flags, bs1, bs2, be1, be2, bo1, bo2, biasf);
  const float *bs1f = biasf, *bs2f = biasf + 3072, *be1f = biasf + 3840,
              *be2f = biasf + 6912, *bo1f = biasf + 7680, *bo2f = biasf + 10752,
              *zerof = biasf + 11520;
  float* outf = (float*)d_out;

  if (tier == 2) {
    // Phase A: token MLPs (start+end merged), hid scratch in R (dead after)
    ushort_t* hidS = (ushort_t*)R;
    ushort_t* hidE = hidS + (size_t)2048 * 3072;
    gemm_bt<false, true, false><<<dim3(16, 48), blk, 0, stream>>>(
        (const bf16*)hb, (const bf16*)hb, nullptr, nullptr, nullptr, 0,
        (const bf16*)w1sb, (const bf16*)w1eb, bs1f, be1f,
        hidS, hidE, 24, 3072, 768, 768);
    gemm_bt<false, true, false><<<dim3(16, 12), blk, 0, stream>>>(
        (const bf16*)hidS, (const bf16*)hidE, nullptr, nullptr, nullptr, 0,
        (const bf16*)w2sb, (const bf16*)w2eb, bs2f, be2f,
        (bf16*)repS, (bf16*)repE, 6, 768, 3072, 3072);
    // Phase B': P_s = repS@wo1[:, :768]^T + bo1 ; P_e = repE@wo1[:, 768:]^T
    // (bf16 P: halves gather traffic in the fused final GEMM)
    ushort_t* Ps = (ushort_t*)R;
    ushort_t* Pe = Ps + (size_t)2048 * 3072;
    gemm_bt<false, false, false><<<dim3(16, 48), blk, 0, stream>>>(
        (const bf16*)repS, (const bf16*)repE, nullptr, nullptr, nullptr, 0,
        (const bf16*)wo1b, (const bf16*)wo1b + 768, bo1f, zerof,
        Ps, Pe, 24, 3072, 768, 1536);
    gemm_final_fused<<<dim3(192, 6), blk, 0, stream>>>(
        Ps, Pe, idx32, (const bf16*)wo2b, bo2f, outf);
  } else {
    // Tier 3 fallback: two-pass path, chunked in R
    long long cT = (long long)(Rsz / ((size_t)2 * 3072 * 2));
    cT = (cT / 128) * 128; if (cT > 2048) cT = 2048;
    long long cO = (long long)(Rsz / ((size_t)3072 * 2));
    cO = (cO / 128) * 128; if (cO > 24576) cO = 24576;
    if (cT < 128 || cO < 128) return;
    ushort_t* scr = (ushort_t*)R;
    for (long long r = 0; r < 2048; r += cT) {
      long long mc = 2048 - r < cT ? 2048 - r : cT;
      ushort_t* hidS = scr;
      ushort_t* hidE = scr + (size_t)cT * 3072;
      gemm_bt<false, true, false><<<dim3(mc / 128, 48), blk, 0, stream>>>(
          (const bf16*)hb + r * 768, (const bf16*)hb + r * 768,
          nullptr, nullptr, nullptr, 0,
          (const bf16*)w1sb, (const bf16*)w1eb, bs1f, be1f,
          hidS, hidE, 24, 3072, 768, 768);
      gemm_bt<false, true, false><<<dim3(mc / 128, 12), blk, 0, stream>>>(
          (const bf16*)hidS, (const bf16*)hidE, nullptr, nullptr, nullptr, 0,
          (const bf16*)w2sb, (const bf16*)w2eb, bs2f, be2f,
          (bf16*)repS + r * 768, (bf16*)repE + r * 768, 6, 768, 3072, 3072);
    }
    for (long long r = 0; r < 24576; r += cO) {
      long long mc = 24576 - r < cO ? 24576 - r : cO;
      gemm_bt<true, true, false><<<dim3(mc / 128, 24), blk, 0, stream>>>(
          nullptr, nullptr, (const bf16*)repS, (const bf16*)repE, idx32, (int)r,
          (const bf16*)wo1b, nullptr, bo1f, nullptr,
          scr, nullptr, XBIG, 3072, 1536, 1536);
      gemm_bt<false, false, true><<<dim3(mc / 128, 6), blk, 0, stream>>>(
          (const bf16*)scr, nullptr, nullptr, nullptr, nullptr, 0,
          (const bf16*)wo2b, nullptr, bo2f, nullptr,
          outf + (size_t)r * 768, nullptr, XBIG, 768, 3072, 3072);
    }
  }
}

// Round 8
// 558.819 us; speedup vs baseline: 1.4324x; 1.0477x over previous
//
#include <hip/hip_runtime.h>
#include <hip/hip_bf16.h>

using bf16 = __hip_bfloat16;
using bf16x8 = __attribute__((ext_vector_type(8))) __bf16;
using f32x4  = __attribute__((ext_vector_type(4))) float;
typedef unsigned short ushort_t;

#define BM 128
#define BN 128
#define BK 32

// B=4, L=512, D=768, W=12, K_spans=6144, rows_out = B*K = 24576

__device__ __forceinline__ void gl_lds16(const void* g, void* l) {
  __builtin_amdgcn_global_load_lds(
      (const __attribute__((address_space(1))) void*)g,
      (__attribute__((address_space(3))) void*)l, 16, 0, 0);
}

__device__ __forceinline__ ushort_t f2bf(float f) {  // RNE fp32->bf16
  unsigned u = __float_as_uint(f);
  u += 0x7FFF + ((u >> 16) & 1);
  return (ushort_t)(u >> 16);
}

// flags[0]=1 if float inputs are stored as bf16 (else fp32)
// flags[1]=1 if span_idx is int64 (else int32)
__global__ void sniff(const unsigned* __restrict__ w1,
                      const unsigned* __restrict__ idx, int* flags) {
  __shared__ int cnt[2];
  if (threadIdx.x == 0) { cnt[0] = 0; cnt[1] = 0; }
  __syncthreads();
  int t = threadIdx.x;  // 256 threads
  int c0 = 0;
  for (int k = 0; k < 4; ++k) {
    unsigned lo = w1[t * 4 + k] & 0xFFFFu;
    unsigned e = (lo >> 7) & 0xFF;
    if (e <= 122) c0++;
  }
  int c1 = (idx[2 * t + 1] != 0) ? 1 : 0;
  atomicAdd(&cnt[0], c0);
  atomicAdd(&cnt[1], c1);
  __syncthreads();
  if (threadIdx.x == 0) {
    flags[0] = (cnt[0] >= 900) ? 1 : 0;
    flags[1] = (cnt[1] == 0) ? 1 : 0;
  }
}

__global__ void norm_idx(const int* __restrict__ flags, const void* __restrict__ src,
                         int* __restrict__ dst) {
  int i = blockIdx.x * 256 + threadIdx.x;  // grid covers exactly 49152
  int v = flags[1] ? (int)((const long long*)src)[i] : ((const int*)src)[i];
  dst[i] = v;
}

// One kernel converts h + all 6 weights into the contiguous bf16 region at dst.
__global__ void cvt_all(const int* __restrict__ flags,
                        const void* s0, const void* s1, const void* s2,
                        const void* s3, const void* s4, const void* s5,
                        const void* s6, ushort_t* __restrict__ dst) {
  long i = ((long)blockIdx.x * 256 + threadIdx.x) * 4;
  const void* src; long off;
  if      (i <  1572864) { src = s0; off = i; }
  else if (i <  3932160) { src = s1; off = i - 1572864; }
  else if (i <  6291456) { src = s2; off = i - 3932160; }
  else if (i <  8650752) { src = s3; off = i - 6291456; }
  else if (i < 11010048) { src = s4; off = i - 8650752; }
  else if (i < 15728640) { src = s5; off = i - 11010048; }
  else                   { src = s6; off = i - 15728640; }
  if (flags[0]) {
    *(ushort4*)(dst + i) = *((const ushort4*)((const ushort_t*)src + off));
  } else {
    float4 f = ((const float4*)src)[off >> 2];
    ushort4 o;
    o.x = f2bf(f.x); o.y = f2bf(f.y); o.z = f2bf(f.z); o.w = f2bf(f.w);
    *(ushort4*)(dst + i) = o;
  }
}

// biases -> fp32, [bs1|bs2|be1|be2|bo1|bo2|zeros] = 11520 + 3072 floats
__global__ void cvt_bias(const int* __restrict__ flags,
                         const void* b0, const void* b1, const void* b2,
                         const void* b3, const void* b4, const void* b5,
                         float* __restrict__ dst) {
  int i = blockIdx.x * 256 + threadIdx.x;
  if (i >= 14592) return;
  if (i >= 11520) { dst[i] = 0.f; return; }  // zero-bias tail
  const void* src; int off;
  if (i < 3072)       { src = b0; off = i; }
  else if (i < 3840)  { src = b1; off = i - 3072; }
  else if (i < 6912)  { src = b2; off = i - 3840; }
  else if (i < 7680)  { src = b3; off = i - 6912; }
  else if (i < 10752) { src = b4; off = i - 7680; }
  else                { src = b5; off = i - 10752; }
  dst[i] = flags[0] ? __bfloat162float(((const bf16*)src)[off])
                    : ((const float*)src)[off];
}

// C[M,N] = act(A[M,K] @ Bw[N,K(bstride)]^T + bias), A optionally gathered.
// Grid: (m-tiles, n-tiles) — m on blockIdx.x so same-A blocks (diff n) have
// linear ids differing by gridDim.x (mult of 8) -> same XCD -> A L2 reuse.
// Dual-launch: blocks with blockIdx.y >= nsplit use the second operand set.
// LDS k-block XOR swizzle kills the 8-way ds_read_b128 conflict.
template <bool GATHER, bool RELU, bool OUTF32>
__global__ __launch_bounds__(256) void gemm_bt(
    const bf16* __restrict__ A, const bf16* __restrict__ A2,
    const bf16* __restrict__ repS, const bf16* __restrict__ repE,
    const int* __restrict__ sidx, int row_base,
    const bf16* __restrict__ Bw, const bf16* __restrict__ Bw2,
    const float* __restrict__ bias, const float* __restrict__ bias2,
    void* __restrict__ C, void* __restrict__ C2, int nsplit,
    int N, int Kdim, int bstride) {
  __shared__ bf16 lA[BM * BK];
  __shared__ bf16 lB[BN * BK];

  const int tid  = threadIdx.x;
  const int lane = tid & 63;
  const int wave = tid >> 6;
  const int wm = wave >> 1, wn = wave & 1;
  int by = blockIdx.y;
  const bf16* Bw_ = Bw; const float* bias_ = bias; void* C_ = C; const bf16* A_ = A;
  if (by >= nsplit) { by -= nsplit; Bw_ = Bw2; bias_ = bias2; C_ = C2; A_ = A2; }
  const int m0 = blockIdx.x * BM;
  const int n0 = by * BN;

  const int srow = tid >> 2;
  const int scol = 8 * ((tid & 3) ^ ((tid >> 3) & 3));

  const bf16 *a0 = nullptr, *a1 = nullptr;
  const bf16 *pS0 = nullptr, *pE0 = nullptr, *pS1 = nullptr, *pE1 = nullptr;
  if (GATHER) {
    int r0 = row_base + m0 + srow;
    int r1 = r0 + 64;
    int b0 = r0 / 6144, b1 = r1 / 6144;
    int s0 = min(max(sidx[2 * r0], 0), 511);
    int e0 = min(max(sidx[2 * r0 + 1], 0), 511);
    int s1 = min(max(sidx[2 * r1], 0), 511);
    int e1 = min(max(sidx[2 * r1 + 1], 0), 511);
    pS0 = repS + ((size_t)b0 * 512 + s0) * 768 + scol;
    pE0 = repE + ((size_t)b0 * 512 + e0) * 768 + scol;
    pS1 = repS + ((size_t)b1 * 512 + s1) * 768 + scol;
    pE1 = repE + ((size_t)b1 * 512 + e1) * 768 + scol;
  } else {
    a0 = A_ + (size_t)(m0 + srow) * Kdim + scol;
    a1 = a0 + (size_t)64 * Kdim;
  }
  const bf16* b0p = Bw_ + (size_t)(n0 + srow) * bstride + scol;
  const bf16* b1p = b0p + (size_t)64 * bstride;

  f32x4 acc[4][4];
  const f32x4 z = {0.f, 0.f, 0.f, 0.f};
#pragma unroll
  for (int i = 0; i < 4; ++i)
#pragma unroll
    for (int j = 0; j < 4; ++j) acc[i][j] = z;

  const int fr = lane & 15;
  const int fk = 8 * ((lane >> 4) ^ ((lane >> 1) & 3));

  for (int k0 = 0; k0 < Kdim; k0 += BK) {
    const bf16 *sa0, *sa1;
    if (GATHER) {
      if (k0 < 768) { sa0 = pS0 + k0; sa1 = pS1 + k0; }
      else          { sa0 = pE0 + (k0 - 768); sa1 = pE1 + (k0 - 768); }
    } else {
      sa0 = a0 + k0; sa1 = a1 + k0;
    }
    gl_lds16(sa0, lA + tid * 8);
    gl_lds16(sa1, lA + 2048 + tid * 8);
    gl_lds16(b0p + k0, lB + tid * 8);
    gl_lds16(b1p + k0, lB + 2048 + tid * 8);
    __syncthreads();

    bf16x8 af[4], bv[4];
#pragma unroll
    for (int i = 0; i < 4; ++i)
      af[i] = *(const bf16x8*)(const void*)(lA + (wm * 64 + i * 16 + fr) * BK + fk);
#pragma unroll
    for (int j = 0; j < 4; ++j)
      bv[j] = *(const bf16x8*)(const void*)(lB + (wn * 64 + j * 16 + fr) * BK + fk);
#pragma unroll
    for (int i = 0; i < 4; ++i)
#pragma unroll
      for (int j = 0; j < 4; ++j)
        acc[i][j] = __builtin_amdgcn_mfma_f32_16x16x32_bf16(af[i], bv[j], acc[i][j], 0, 0, 0);
    __syncthreads();
  }

  float* Cf = (float*)C_;
  bf16*  Cb = (bf16*)C_;
#pragma unroll
  for (int j = 0; j < 4; ++j) {
    int n = n0 + wn * 64 + j * 16 + fr;
    float bj = bias_[n];
#pragma unroll
    for (int i = 0; i < 4; ++i) {
      int mb = m0 + wm * 64 + i * 16 + (lane >> 4) * 4;
#pragma unroll
      for (int r = 0; r < 4; ++r) {
        float v = acc[i][j][r] + bj;
        if (RELU) v = fmaxf(v, 0.f);
        if (OUTF32) Cf[(size_t)(mb + r) * N + n] = v;
        else        Cb[(size_t)(mb + r) * N + n] = __float2bfloat16(v);
      }
    }
  }
}

// Final GEMM, fused gather-add-relu A-staging, software-pipelined:
//   A[r][k] = relu(Ps[tok_s(r)][k] + Pe[tok_e(r)][k]),  out = A @ wo2^T + bo2
// Ps/Pe [2048][3072] bf16. N=768, K=3072. Grid (192, 6).
// LDS double-buffered; per iter: issue loads for k+1 -> MFMA on k -> pack k+1.
// Scattered-load latency overlaps the MFMA phase instead of preceding it.
__global__ __launch_bounds__(256) void gemm_final_fused(
    const ushort_t* __restrict__ Ps, const ushort_t* __restrict__ Pe,
    const int* __restrict__ sidx,
    const bf16* __restrict__ Bw, const float* __restrict__ bias,
    float* __restrict__ out) {
  __shared__ bf16 lA[2 * 4096];  // 16 KB (two 128x32 buffers)
  __shared__ bf16 lB[2 * 4096];  // 16 KB

  const int tid  = threadIdx.x;
  const int lane = tid & 63;
  const int wave = tid >> 6;
  const int wm = wave >> 1, wn = wave & 1;
  const int m0 = blockIdx.x * BM;
  const int n0 = blockIdx.y * BN;

  const int srow = tid >> 2;
  const int scol = 8 * ((tid & 3) ^ ((tid >> 3) & 3));

  int r0 = m0 + srow, r1 = r0 + 64;
  int b0 = r0 / 6144, b1 = r1 / 6144;
  int s0 = min(max(sidx[2 * r0], 0), 511);
  int e0 = min(max(sidx[2 * r0 + 1], 0), 511);
  int s1 = min(max(sidx[2 * r1], 0), 511);
  int e1 = min(max(sidx[2 * r1 + 1], 0), 511);
  const ushort_t* pS0 = Ps + ((size_t)b0 * 512 + s0) * 3072 + scol;
  const ushort_t* pE0 = Pe + ((size_t)b0 * 512 + e0) * 3072 + scol;
  const ushort_t* pS1 = Ps + ((size_t)b1 * 512 + s1) * 3072 + scol;
  const ushort_t* pE1 = Pe + ((size_t)b1 * 512 + e1) * 3072 + scol;

  const bf16* bp0 = Bw + (size_t)(n0 + srow) * 3072 + scol;
  const bf16* bp1 = bp0 + (size_t)64 * 3072;

  f32x4 acc[4][4];
  const f32x4 z = {0.f, 0.f, 0.f, 0.f};
#pragma unroll
  for (int i = 0; i < 4; ++i)
#pragma unroll
    for (int j = 0; j < 4; ++j) acc[i][j] = z;

  const int fr = lane & 15;
  const int fk = 8 * ((lane >> 4) ^ ((lane >> 1) & 3));

  // pack two gathered 16B chunks -> relu'd bf16x8 -> LDS
  auto pack_store = [&](uint4 xs, uint4 xe, bf16* dst) {
    unsigned w[4];
    const unsigned* us = &xs.x;
    const unsigned* ue = &xe.x;
#pragma unroll
    for (int q = 0; q < 4; ++q) {
      float lo = __uint_as_float(us[q] << 16) + __uint_as_float(ue[q] << 16);
      float hi = __uint_as_float(us[q] & 0xFFFF0000u) +
                 __uint_as_float(ue[q] & 0xFFFF0000u);
      w[q] = (unsigned)f2bf(fmaxf(lo, 0.f)) |
             ((unsigned)f2bf(fmaxf(hi, 0.f)) << 16);
    }
    *(uint4*)(void*)dst = *(const uint4*)w;
  };

  // ---- prologue: stage tile 0 into buffer 0 ----
  {
    gl_lds16(bp0, lB + tid * 8);
    gl_lds16(bp1, lB + 2048 + tid * 8);
    uint4 xs0 = *(const uint4*)(const void*)pS0;
    uint4 xe0 = *(const uint4*)(const void*)pE0;
    uint4 xs1 = *(const uint4*)(const void*)pS1;
    uint4 xe1 = *(const uint4*)(const void*)pE1;
    pack_store(xs0, xe0, lA + tid * 8);
    pack_store(xs1, xe1, lA + 2048 + tid * 8);
    __syncthreads();
  }

  for (int it = 0; it < 96; ++it) {
    const int cur = (it & 1) << 12;
    const int nxt = ((it + 1) & 1) << 12;
    const int k1 = (it + 1) * BK;
    const bool pre = (it + 1) < 96;
    uint4 xs0, xe0, xs1, xe1;
    if (pre) {  // issue next tile's loads BEFORE the MFMA block
      gl_lds16(bp0 + k1, lB + nxt + tid * 8);
      gl_lds16(bp1 + k1, lB + nxt + 2048 + tid * 8);
      xs0 = *(const uint4*)(const void*)(pS0 + k1);
      xe0 = *(const uint4*)(const void*)(pE0 + k1);
      xs1 = *(const uint4*)(const void*)(pS1 + k1);
      xe1 = *(const uint4*)(const void*)(pE1 + k1);
    }

    bf16x8 af[4], bv[4];
#pragma unroll
    for (int i = 0; i < 4; ++i)
      af[i] = *(const bf16x8*)(const void*)(lA + cur + (wm * 64 + i * 16 + fr) * BK + fk);
#pragma unroll
    for (int j = 0; j < 4; ++j)
      bv[j] = *(const bf16x8*)(const void*)(lB + cur + (wn * 64 + j * 16 + fr) * BK + fk);
#pragma unroll
    for (int i = 0; i < 4; ++i)
#pragma unroll
      for (int j = 0; j < 4; ++j)
        acc[i][j] = __builtin_amdgcn_mfma_f32_16x16x32_bf16(af[i], bv[j], acc[i][j], 0, 0, 0);

    if (pre) {  // wait for loads (overlapped with MFMA above), pack, store
      pack_store(xs0, xe0, lA + nxt + tid * 8);
      pack_store(xs1, xe1, lA + nxt + 2048 + tid * 8);
    }
    __syncthreads();
  }

#pragma unroll
  for (int j = 0; j < 4; ++j) {
    int n = n0 + wn * 64 + j * 16 + fr;
    float bj = bias[n];
#pragma unroll
    for (int i = 0; i < 4; ++i) {
      int mb = m0 + wm * 64 + i * 16 + (lane >> 4) * 4;
#pragma unroll
      for (int r = 0; r < 4; ++r)
        out[(size_t)(mb + r) * 768 + n] = acc[i][j][r] + bj;
    }
  }
}

extern "C" void kernel_launch(void* const* d_in, const int* in_sizes, int n_in,
                              void* d_out, int out_size, void* d_ws, size_t ws_size,
                              hipStream_t stream) {
  const void* h    = d_in[0];
  const void* sidx = d_in[1];
  const void *ws1 = d_in[2],  *bs1 = d_in[3];
  const void *ws2 = d_in[4],  *bs2 = d_in[5];
  const void *we1 = d_in[6],  *be1 = d_in[7];
  const void *we2 = d_in[8],  *be2 = d_in[9];
  const void *wo1 = d_in[10], *bo1 = d_in[11];
  const void *wo2 = d_in[12], *bo2 = d_in[13];

  // ---- fixed workspace region ----
  char* p = (char*)d_ws;
  int*      flags = (int*)p;
  int*      idx32 = (int*)(p + 256);
  float*    biasf = (float*)(p + 256 + 196608);            // 14592 f32 (incl zeros)
  ushort_t* hb    = (ushort_t*)(p + 256 + 196608 + 65536);
  ushort_t* w1sb  = hb   + (size_t)1572864;
  ushort_t* w2sb  = w1sb + (size_t)2359296;
  ushort_t* w1eb  = w2sb + (size_t)2359296;
  ushort_t* w2eb  = w1eb + (size_t)2359296;
  ushort_t* wo1b  = w2eb + (size_t)2359296;
  ushort_t* wo2b  = wo1b + (size_t)4718592;
  ushort_t* repS  = wo2b + (size_t)2359296;
  ushort_t* repE  = repS + (size_t)1572864;
  char*     R     = (char*)(repE + (size_t)1572864);  // transient region
  size_t fixed = (size_t)(R - (char*)d_ws);
  if (ws_size < fixed) return;
  size_t Rsz = ws_size - fixed;

  const size_t P_BF = (size_t)2 * 2048 * 3072 * 2;  // Ps+Pe bf16 (== phase-A hid)
  int tier = (Rsz >= P_BF) ? 2 : 3;

  dim3 blk(256);
  const int XBIG = 0x40000000;
  sniff<<<1, blk, 0, stream>>>((const unsigned*)ws1, (const unsigned*)sidx, flags);
  norm_idx<<<192, blk, 0, stream>>>(flags, sidx, idx32);
  cvt_all<<<17664, blk, 0, stream>>>(flags, h, ws1, ws2, we1, we2, wo1, wo2, hb);
  cvt_bias<<<57, blk, 0, stream>>>(flags, bs1, bs2, be1, be2, bo1, bo2, biasf);
  const float *bs1f = biasf, *bs2f = biasf + 3072, *be1f = biasf + 3840,
              *be2f = biasf + 6912, *bo1f = biasf + 7680, *bo2f = biasf + 10752,
              *zerof = biasf + 11520;
  float* outf = (float*)d_out;

  if (tier == 2) {
    // Phase A: token MLPs (start+end merged), hid scratch in R (dead after)
    ushort_t* hidS = (ushort_t*)R;
    ushort_t* hidE = hidS + (size_t)2048 * 3072;
    gemm_bt<false, true, false><<<dim3(16, 48), blk, 0, stream>>>(
        (const bf16*)hb, (const bf16*)hb, nullptr, nullptr, nullptr, 0,
        (const bf16*)w1sb, (const bf16*)w1eb, bs1f, be1f,
        hidS, hidE, 24, 3072, 768, 768);
    gemm_bt<false, true, false><<<dim3(16, 12), blk, 0, stream>>>(
        (const bf16*)hidS, (const bf16*)hidE, nullptr, nullptr, nullptr, 0,
        (const bf16*)w2sb, (const bf16*)w2eb, bs2f, be2f,
        (bf16*)repS, (bf16*)repE, 6, 768, 3072, 3072);
    // Phase B': P_s = repS@wo1[:, :768]^T + bo1 ; P_e = repE@wo1[:, 768:]^T
    ushort_t* Ps = (ushort_t*)R;
    ushort_t* Pe = Ps + (size_t)2048 * 3072;
    gemm_bt<false, false, false><<<dim3(16, 48), blk, 0, stream>>>(
        (const bf16*)repS, (const bf16*)repE, nullptr, nullptr, nullptr, 0,
        (const bf16*)wo1b, (const bf16*)wo1b + 768, bo1f, zerof,
        Ps, Pe, 24, 3072, 768, 1536);
    gemm_final_fused<<<dim3(192, 6), blk, 0, stream>>>(
        Ps, Pe, idx32, (const bf16*)wo2b, bo2f, outf);
  } else {
    // Tier 3 fallback: two-pass path, chunked in R
    long long cT = (long long)(Rsz / ((size_t)2 * 3072 * 2));
    cT = (cT / 128) * 128; if (cT > 2048) cT = 2048;
    long long cO = (long long)(Rsz / ((size_t)3072 * 2));
    cO = (cO / 128) * 128; if (cO > 24576) cO = 24576;
    if (cT < 128 || cO < 128) return;
    ushort_t* scr = (ushort_t*)R;
    for (long long r = 0; r < 2048; r += cT) {
      long long mc = 2048 - r < cT ? 2048 - r : cT;
      ushort_t* hidS = scr;
      ushort_t* hidE = scr + (size_t)cT * 3072;
      gemm_bt<false, true, false><<<dim3(mc / 128, 48), blk, 0, stream>>>(
          (const bf16*)hb + r * 768, (const bf16*)hb + r * 768,
          nullptr, nullptr, nullptr, 0,
          (const bf16*)w1sb, (const bf16*)w1eb, bs1f, be1f,
          hidS, hidE, 24, 3072, 768, 768);
      gemm_bt<false, true, false><<<dim3(mc / 128, 12), blk, 0, stream>>>(
          (const bf16*)hidS, (const bf16*)hidE, nullptr, nullptr, nullptr, 0,
          (const bf16*)w2sb, (const bf16*)w2eb, bs2f, be2f,
          (bf16*)repS + r * 768, (bf16*)repE + r * 768, 6, 768, 3072, 3072);
    }
    for (long long r = 0; r < 24576; r += cO) {
      long long mc = 24576 - r < cO ? 24576 - r : cO;
      gemm_bt<true, true, false><<<dim3(mc / 128, 24), blk, 0, stream>>>(
          nullptr, nullptr, (const bf16*)repS, (const bf16*)repE, idx32, (int)r,
          (const bf16*)wo1b, nullptr, bo1f, nullptr,
          scr, nullptr, XBIG, 3072, 1536, 1536);
      gemm_bt<false, false, true><<<dim3(mc / 128, 6), blk, 0, stream>>>(
          (const bf16*)scr, nullptr, nullptr, nullptr, nullptr, 0,
          (const bf16*)wo2b, nullptr, bo2f, nullptr,
          outf + (size_t)r * 768, nullptr, XBIG, 768, 3072, 3072);
    }
  }
}